// Round 6
// baseline (5897.289 us; speedup 1.0000x reference)
//
#include <hip/hip_runtime.h>
#include <hip/hip_fp16.h>

typedef unsigned int u32;
typedef u32 u32x16 __attribute__((ext_vector_type(16)));

#define TT 2048
#define HD 256
#define G4 1024
#define NT 16
#define START_TAG 14
#define STOP_TAG 15
#define NEGV (-10000.0f)

typedef _Float16 half2v __attribute__((ext_vector_type(2)));

__device__ __forceinline__ float fdot2u(u32 a, u32 b, float c) {
    return __builtin_amdgcn_fdot2(__builtin_bit_cast(half2v, a),
                                  __builtin_bit_cast(half2v, b), c, false);
}
__device__ __forceinline__ float sigmf_(float x) { return 1.0f / (1.0f + __expf(-x)); }
__device__ __forceinline__ float tanhf_(float x) {
    float e = __expf(-2.0f * fabsf(x));
    return copysignf((1.0f - e) / (1.0f + e), x);
}

// K0: pack w_hh to f16 pairs. Register part [dir][1024][96] (u32 pair p = K 2p,2p+1).
// LDS part (p=96..127): b64-pair layout: wldsp[dir*32K + (k2*1024 + row)*2 + half].
__global__ __launch_bounds__(128) void pack_whh(const float* whh_f, const float* whh_b,
                                                u32* wregp, u32* wldsp) {
    int row = blockIdx.x, dir = blockIdx.y, k = threadIdx.x;
    const float* w = (dir ? whh_b : whh_f) + (size_t)row * HD;
    if (k < 96) {
        u32 lo = __half_as_ushort(__float2half(w[2 * k]));
        u32 hi = __half_as_ushort(__float2half(w[2 * k + 1]));
        wregp[((size_t)dir * G4 + row) * 96 + k] = lo | (hi << 16);
    } else {
        int q = k - 96;                        // 0..31
        int k2 = q >> 1, half = q & 1;
        u32 lo = __half_as_ushort(__float2half(w[192 + 2 * q]));
        u32 hi = __half_as_ushort(__float2half(w[193 + 2 * q]));
        wldsp[(size_t)dir * 32 * G4 + ((size_t)k2 * G4 + row) * 2 + half] = lo | (hi << 16);
    }
}

// K1: G[dir][t][r] = dot(embed[sent[t or T-1-t]], w_ih[r]) + b[r]   (f32 exact)
__global__ __launch_bounds__(256) void input_gemm(const int* sent, const float* embed,
                                                  const float* wih_f, const float* b_f,
                                                  const float* wih_b, const float* b_b,
                                                  float* G) {
    __shared__ float X[32][HD];   // 32KB
    __shared__ int rows[32];
    int tid = threadIdx.x;
    int dir = blockIdx.z;
    int t0 = blockIdx.x * 32;
    if (tid < 32) {
        int tg = t0 + tid;
        rows[tid] = sent[dir ? (TT - 1 - tg) : tg];
    }
    __syncthreads();
    for (int i = 0; i < 32; i++) X[i][tid] = embed[(size_t)rows[i] * HD + tid];
    __syncthreads();
    int r = blockIdx.y * 256 + tid;
    const float* wrow = (dir ? wih_b : wih_f) + (size_t)r * HD;
    float acc[32];
#pragma unroll
    for (int i = 0; i < 32; i++) acc[i] = 0.0f;
    for (int kc = 0; kc < HD / 4; kc++) {
        float4 w4 = ((const float4*)wrow)[kc];
#pragma unroll
        for (int i = 0; i < 32; i++) {
            float4 x4 = *((const float4*)&X[i][kc * 4]);
            acc[i] += w4.x * x4.x + w4.y * x4.y + w4.z * x4.z + w4.w * x4.w;
        }
    }
    float bias = (dir ? b_b : b_f)[r];
    for (int i = 0; i < 32; i++)
        G[((size_t)dir * TT + t0 + i) * G4 + r] = acc[i] + bias;
}

// two-row dot block: W0/W1 hold K pairs B..B+15 of rows tid / tid+512; one
// h-broadcast read feeds both accumulator chains (a0, a1 independent -> ILP).
#define DOT16_2(W0, W1, B)                                                    \
    {                                                                         \
        uint4 ha = *((const uint4*)&h2[(B)]);                                 \
        a0 = fdot2u(W0[0], ha.x, a0);  a1 = fdot2u(W1[0], ha.x, a1);          \
        a0 = fdot2u(W0[1], ha.y, a0);  a1 = fdot2u(W1[1], ha.y, a1);          \
        a0 = fdot2u(W0[2], ha.z, a0);  a1 = fdot2u(W1[2], ha.z, a1);          \
        a0 = fdot2u(W0[3], ha.w, a0);  a1 = fdot2u(W1[3], ha.w, a1);          \
        uint4 hb = *((const uint4*)&h2[(B) + 4]);                             \
        a0 = fdot2u(W0[4], hb.x, a0);  a1 = fdot2u(W1[4], hb.x, a1);          \
        a0 = fdot2u(W0[5], hb.y, a0);  a1 = fdot2u(W1[5], hb.y, a1);          \
        a0 = fdot2u(W0[6], hb.z, a0);  a1 = fdot2u(W1[6], hb.z, a1);          \
        a0 = fdot2u(W0[7], hb.w, a0);  a1 = fdot2u(W1[7], hb.w, a1);          \
        uint4 hc = *((const uint4*)&h2[(B) + 8]);                             \
        a0 = fdot2u(W0[8], hc.x, a0);  a1 = fdot2u(W1[8], hc.x, a1);          \
        a0 = fdot2u(W0[9], hc.y, a0);  a1 = fdot2u(W1[9], hc.y, a1);          \
        a0 = fdot2u(W0[10], hc.z, a0); a1 = fdot2u(W1[10], hc.z, a1);         \
        a0 = fdot2u(W0[11], hc.w, a0); a1 = fdot2u(W1[11], hc.w, a1);         \
        uint4 hd = *((const uint4*)&h2[(B) + 12]);                            \
        a0 = fdot2u(W0[12], hd.x, a0); a1 = fdot2u(W1[12], hd.x, a1);         \
        a0 = fdot2u(W0[13], hd.y, a0); a1 = fdot2u(W1[13], hd.y, a1);         \
        a0 = fdot2u(W0[14], hd.z, a0); a1 = fdot2u(W1[14], hd.z, a1);         \
        a0 = fdot2u(W0[15], hd.w, a0); a1 = fdot2u(W1[15], hd.w, a1);         \
    }

// K2: persistent per-direction LSTM recurrence. 512 threads, 2 gate rows each
// (rows tid, tid+512): thread j<256 owns (i_j,g_j), thread j+256 owns (f_j,o_j).
// Weights K=0..191 in TWELVE NAMED u32x16 SSA values (192 VGPRs, never memory);
// K=192..255 via LDS b64-pair reads. Demand ~232 regs.
// __launch_bounds__(512,1): every candidate semantic for arg2 (min waves/EU=1,
// 1 block/CU, etc.) yields a VGPR cap >= 256 -> no spill. (1024-thread variants
// were hard-capped at 64 in R1/R4/R5; waves_per_eu attribute proved inert.)
__global__ __launch_bounds__(512, 1)
void lstm_rec(const u32* wregp, const u32* wldsp,
              const float* G, const float* h0,
              const float* c0, float* H) {
    __shared__ u32 Wl[32 * G4];            // 128KB, layout [16][1024][2]
    __shared__ float fo[2][256];           // sig(f), sig(o) exchange
    __shared__ __align__(16) u32 h2[128];  // 256 f16 of h (u32 p = h[2p],h[2p+1])
    int tid = threadIdx.x;
    int dir = blockIdx.x;
    {   // stage LDS weight slice, vectorized (linear copy preserves layout)
        const uint4* src = (const uint4*)(wldsp + (size_t)dir * 32 * G4);
        uint4* dst = (uint4*)Wl;
        for (int i = tid; i < 32 * G4 / 4; i += 512) dst[i] = src[i];
    }
    const u32x16* wp0 = (const u32x16*)(wregp + ((size_t)dir * G4 + tid) * 96);
    const u32x16* wp1 = (const u32x16*)(wregp + ((size_t)dir * G4 + tid + 512) * 96);
    u32x16 wA0 = wp0[0], wB0 = wp0[1], wC0 = wp0[2], wD0 = wp0[3], wE0 = wp0[4], wF0 = wp0[5];
    u32x16 wA1 = wp1[0], wB1 = wp1[1], wC1 = wp1[2], wD1 = wp1[3], wE1 = wp1[4], wF1 = wp1[5];
    float cst = 0.0f;
    if (tid < HD) {
        cst = c0[dir * HD + tid];
        ((unsigned short*)h2)[tid] = __half_as_ushort(__float2half(h0[dir * HD + tid]));
    }
    __syncthreads();
    const float* Gd = G + (size_t)dir * TT * G4;
    float* Hd = H + (size_t)dir * TT * HD;
    for (int t = 0; t < TT; t++) {
        float g0 = Gd[(size_t)t * G4 + tid];          // issued early
        float g1 = Gd[(size_t)t * G4 + tid + 512];
        float a0 = 0.0f, a1 = 0.0f;
        DOT16_2(wA0, wA1, 0)  DOT16_2(wB0, wB1, 16) DOT16_2(wC0, wC1, 32)
        DOT16_2(wD0, wD1, 48) DOT16_2(wE0, wE1, 64) DOT16_2(wF0, wF1, 80)
#pragma unroll
        for (int k2 = 0; k2 < 16; k2 += 2) {   // K tail from LDS, b64 reads
            uint4 hh = *((const uint4*)&h2[96 + 2 * k2]);
            uint2 pa = *((const uint2*)&Wl[((size_t)k2 * G4 + tid) * 2]);
            uint2 qa = *((const uint2*)&Wl[((size_t)k2 * G4 + tid + 512) * 2]);
            a0 = fdot2u(pa.x, hh.x, a0);  a1 = fdot2u(qa.x, hh.x, a1);
            a0 = fdot2u(pa.y, hh.y, a0);  a1 = fdot2u(qa.y, hh.y, a1);
            uint2 pb = *((const uint2*)&Wl[(((size_t)k2 + 1) * G4 + tid) * 2]);
            uint2 qb = *((const uint2*)&Wl[(((size_t)k2 + 1) * G4 + tid + 512) * 2]);
            a0 = fdot2u(pb.x, hh.z, a0);  a1 = fdot2u(qb.x, hh.z, a1);
            a0 = fdot2u(pb.y, hh.w, a0);  a1 = fdot2u(qb.y, hh.w, a1);
        }
        a0 += g0; a1 += g1;
        if (tid >= 256) {                    // a0 = f_j, a1 = o_j  (j = tid-256)
            fo[0][tid - 256] = sigmf_(a0);
            fo[1][tid - 256] = sigmf_(a1);
        }
        __syncthreads();
        if (tid < 256) {                     // a0 = i_j, a1 = g_j  (j = tid)
            float sf = fo[0][tid], so = fo[1][tid];
            cst = sf * cst + sigmf_(a0) * tanhf_(a1);
            float h = so * tanhf_(cst);
            Hd[(size_t)t * HD + tid] = h;
            ((unsigned short*)h2)[tid] = __half_as_ushort(__float2half(h));
        }
        __syncthreads();
    }
}

// K3: feats[t][n] = hf[t]·w_out[n][0:256] + hb_scan[T-1-t]·w_out[n][256:512] + b_out[n]
__global__ __launch_bounds__(256) void feats_kernel(const float* H, const float* w_out,
                                                    const float* b_out, float* feats) {
    int idx = blockIdx.x * blockDim.x + threadIdx.x;
    int t = idx >> 4, n = idx & 15;
    const float* hf = H + (size_t)t * HD;
    const float* hb = H + ((size_t)TT + (TT - 1 - t)) * HD;
    const float* w = w_out + (size_t)n * (2 * HD);
    float a = b_out[n];
    for (int k = 0; k < HD; k += 4) {
        float4 h4 = *((const float4*)&hf[k]);
        float4 w4 = *((const float4*)&w[k]);
        a += h4.x * w4.x + h4.y * w4.y + h4.z * w4.z + h4.w * w4.w;
    }
    for (int k = 0; k < HD; k += 4) {
        float4 h4 = *((const float4*)&hb[k]);
        float4 w4 = *((const float4*)&w[HD + k]);
        a += h4.x * w4.x + h4.y * w4.y + h4.z * w4.z + h4.w * w4.w;
    }
    feats[(size_t)t * NT + n] = a;
}

// K4: Viterbi + backtrack, single wave, shuffle-only recurrence.
// feats staged into LDS in 256-step chunks.
__global__ __launch_bounds__(64) void viterbi_kernel(const float* feats, const float* trans,
                                                     float* out) {
    __shared__ float fl[4096];              // 16KB: 256 steps x 16 tags
    __shared__ float fvs[NT];
    __shared__ unsigned char bps[TT][NT];   // 32KB
    int lane = threadIdx.x;
    int n = lane >> 2, pg = lane & 3;
    float4 tr4 = *((const float4*)&trans[n * NT + pg * 4]);
    float fv = (lane == START_TAG) ? 0.0f : NEGV;
    for (int c = 0; c < TT / 256; c++) {
        float4 st[16];
        const float4* src = (const float4*)(feats + c * 4096);
#pragma unroll
        for (int i = 0; i < 16; i++) st[i] = src[i * 64 + lane];
#pragma unroll
        for (int i = 0; i < 16; i++) *((float4*)&fl[(i * 64 + lane) * 4]) = st[i];
        __syncthreads();
        for (int tt = 0; tt < 256; tt++) {
            int t = c * 256 + tt;
            float f0 = __shfl(fv, pg * 4 + 0, 64);
            float f1 = __shfl(fv, pg * 4 + 1, 64);
            float f2 = __shfl(fv, pg * 4 + 2, 64);
            float f3 = __shfl(fv, pg * 4 + 3, 64);
            float ft = fl[tt * 16 + n];
            float v = f0 + tr4.x; int bi = pg * 4 + 0;
            float v1 = f1 + tr4.y; if (v1 > v) { v = v1; bi = pg * 4 + 1; }
            float v2 = f2 + tr4.z; if (v2 > v) { v = v2; bi = pg * 4 + 2; }
            float v3 = f3 + tr4.w; if (v3 > v) { v = v3; bi = pg * 4 + 3; }
#pragma unroll
            for (int m = 1; m <= 2; m <<= 1) {   // first-index tie-break
                float ov = __shfl_xor(v, m, 64);
                int ob = __shfl_xor(bi, m, 64);
                if (ov > v || (ov == v && ob < bi)) { v = ov; bi = ob; }
            }
            if (pg == 0) bps[t][n] = (unsigned char)bi;
            fv = __shfl(v + ft, (lane & 15) * 4, 64);
        }
        __syncthreads();
    }
    if (lane < NT) fvs[lane] = fv;
    __syncthreads();
    if (lane == 0) {
        float best = -3.0e38f; int bt = 0;
        for (int p = 0; p < NT; p++) {
            float tv = fvs[p] + trans[STOP_TAG * NT + p];
            if (tv > best) { best = tv; bt = p; }
        }
        out[0] = best;
        int tag = bt;
        out[TT] = (float)tag;                  // path[T-1]
        for (int t = TT - 2; t >= 0; t--) {
            tag = bps[t + 1][tag];
            out[1 + t] = (float)tag;
        }
    }
}

extern "C" void kernel_launch(void* const* d_in, const int* in_sizes, int n_in,
                              void* d_out, int out_size, void* d_ws, size_t ws_size,
                              hipStream_t stream) {
    const int* sent = (const int*)d_in[0];
    const float* embed = (const float*)d_in[1];
    const float* wih_f = (const float*)d_in[2];
    const float* whh_f = (const float*)d_in[3];
    const float* b_f = (const float*)d_in[4];
    const float* wih_b = (const float*)d_in[5];
    const float* whh_b = (const float*)d_in[6];
    const float* b_b = (const float*)d_in[7];
    const float* w_out = (const float*)d_in[8];
    const float* b_out = (const float*)d_in[9];
    const float* trans = (const float*)d_in[10];
    const float* h0 = (const float*)d_in[11];
    const float* c0 = (const float*)d_in[12];
    float* out = (float*)d_out;
    char* ws = (char*)d_ws;

    float* G = (float*)(ws);                               // 16MB
    float* H = (float*)(ws + (size_t)16 * 1024 * 1024);    // 4MB
    float* feats = (float*)(ws + (size_t)20 * 1024 * 1024);// 128KB
    u32* wregp = (u32*)(ws + (size_t)21 * 1024 * 1024);    // 768KB
    u32* wldsp = (u32*)(ws + (size_t)22 * 1024 * 1024);    // 256KB

    pack_whh<<<dim3(G4, 2), 128, 0, stream>>>(whh_f, whh_b, wregp, wldsp);
    input_gemm<<<dim3(TT / 32, G4 / 256, 2), 256, 0, stream>>>(sent, embed, wih_f, b_f,
                                                               wih_b, b_b, G);
    lstm_rec<<<dim3(2), 512, 0, stream>>>(wregp, wldsp, G, h0, c0, H);
    feats_kernel<<<dim3(TT * NT / 256), 256, 0, stream>>>(H, w_out, b_out, feats);
    viterbi_kernel<<<dim3(1), 64, 0, stream>>>(feats, trans, out);
}

// Round 7
// 2883.503 us; speedup vs baseline: 2.0452x; 2.0452x over previous
//
#include <hip/hip_runtime.h>

typedef unsigned int u32;
typedef u32 u32x8 __attribute__((ext_vector_type(8)));

#define TT 2048
#define HD 256
#define G4 1024
#define NT 16
#define START_TAG 14
#define STOP_TAG 15
#define NEGV (-10000.0f)

__device__ __forceinline__ int sdot4e(u32 a, u32 b, int c) {
#if __has_builtin(__builtin_amdgcn_sdot4)
    return __builtin_amdgcn_sdot4((int)a, (int)b, c, false);
#else
    c += (int)(signed char)(a & 255) * (int)(signed char)(b & 255);
    c += (int)(signed char)((a >> 8) & 255) * (int)(signed char)((b >> 8) & 255);
    c += (int)(signed char)((a >> 16) & 255) * (int)(signed char)((b >> 16) & 255);
    c += (int)(signed char)(a >> 24) * (int)(signed char)(b >> 24);
    return c;
#endif
}
__device__ __forceinline__ float sigmf_(float x) { return 1.0f / (1.0f + __expf(-x)); }
__device__ __forceinline__ float tanhf_(float x) {
    float e = __expf(-2.0f * fabsf(x));
    return copysignf((1.0f - e) / (1.0f + e), x);
}

// K0: quantize w_hh to int8, per-row scale. One wave per row (lane = u32 index,
// covering elems 4*lane..4*lane+3). u32 j<40 -> reg file, j>=40 -> LDS file.
__global__ __launch_bounds__(256) void pack_q8(const float* whh_f, const float* whh_b,
                                               u32* wreg8, u32* wlds8, float* rowscale) {
    int lane = threadIdx.x & 63;
    int row = blockIdx.x * 4 + (threadIdx.x >> 6);   // 0..2047
    int dir = row >> 10, r = row & 1023;
    const float* w = (dir ? whh_b : whh_f) + (size_t)r * HD + lane * 4;
    float4 v = *((const float4*)w);
    float m = fmaxf(fmaxf(fabsf(v.x), fabsf(v.y)), fmaxf(fabsf(v.z), fabsf(v.w)));
    for (int off = 1; off < 64; off <<= 1) m = fmaxf(m, __shfl_xor(m, off, 64));
    float invs = m > 0.f ? 127.f / m : 0.f;
    int q0 = (int)rintf(v.x * invs), q1 = (int)rintf(v.y * invs);
    int q2 = (int)rintf(v.z * invs), q3 = (int)rintf(v.w * invs);
    u32 pk = (u32)(q0 & 255) | ((u32)(q1 & 255) << 8) |
             ((u32)(q2 & 255) << 16) | ((u32)(q3 & 255) << 24);
    if (lane < 40) {
        wreg8[((size_t)(dir * 1024 + r)) * 40 + lane] = pk;
    } else {
        int j = lane - 40, q = j >> 1, half = j & 1;
        wlds8[(((size_t)(dir * 12 + q)) * 1024 + r) * 2 + half] = pk;
    }
    if (lane == 0) rowscale[dir * 1024 + r] = m * (1.0f / (127.f * 64.f));
}

// K1: G[dir][t][r] = dot(embed[sent[t or T-1-t]], w_ih[r]) + b[r]   (f32 exact)
__global__ __launch_bounds__(256) void input_gemm(const int* sent, const float* embed,
                                                  const float* wih_f, const float* b_f,
                                                  const float* wih_b, const float* b_b,
                                                  float* G) {
    __shared__ float X[32][HD];   // 32KB
    __shared__ int rows[32];
    int tid = threadIdx.x;
    int dir = blockIdx.z;
    int t0 = blockIdx.x * 32;
    if (tid < 32) {
        int tg = t0 + tid;
        rows[tid] = sent[dir ? (TT - 1 - tg) : tg];
    }
    __syncthreads();
    for (int i = 0; i < 32; i++) X[i][tid] = embed[(size_t)rows[i] * HD + tid];
    __syncthreads();
    int r = blockIdx.y * 256 + tid;
    const float* wrow = (dir ? wih_b : wih_f) + (size_t)r * HD;
    float acc[32];
#pragma unroll
    for (int i = 0; i < 32; i++) acc[i] = 0.0f;
    for (int kc = 0; kc < HD / 4; kc++) {
        float4 w4 = ((const float4*)wrow)[kc];
#pragma unroll
        for (int i = 0; i < 32; i++) {
            float4 x4 = *((const float4*)&X[i][kc * 4]);
            acc[i] += w4.x * x4.x + w4.y * x4.y + w4.z * x4.z + w4.w * x4.w;
        }
    }
    float bias = (dir ? b_b : b_f)[r];
    for (int i = 0; i < 32; i++)
        G[((size_t)dir * TT + t0 + i) * G4 + r] = acc[i] + bias;
}

// int8 dot block: W0/W1 = 8 u32 (32 int8) of rows tid / tid+512; h2q[HB..HB+7].
#define DOTQ(W0, W1, HB)                                                      \
    {                                                                         \
        uint4 pa = *((const uint4*)&h2q[(HB)]);                               \
        acc0 = sdot4e(W0[0], pa.x, acc0); acc1 = sdot4e(W1[0], pa.x, acc1);   \
        acc0 = sdot4e(W0[1], pa.y, acc0); acc1 = sdot4e(W1[1], pa.y, acc1);   \
        acc0 = sdot4e(W0[2], pa.z, acc0); acc1 = sdot4e(W1[2], pa.z, acc1);   \
        acc0 = sdot4e(W0[3], pa.w, acc0); acc1 = sdot4e(W1[3], pa.w, acc1);   \
        uint4 pb = *((const uint4*)&h2q[(HB) + 4]);                           \
        acc0 = sdot4e(W0[4], pb.x, acc0); acc1 = sdot4e(W1[4], pb.x, acc1);   \
        acc0 = sdot4e(W0[5], pb.y, acc0); acc1 = sdot4e(W1[5], pb.y, acc1);   \
        acc0 = sdot4e(W0[6], pb.z, acc0); acc1 = sdot4e(W1[6], pb.z, acc1);   \
        acc0 = sdot4e(W0[7], pb.w, acc0); acc1 = sdot4e(W1[7], pb.w, acc1);   \
    }

// K2: persistent per-direction LSTM recurrence, int8 weights (v_dot4).
// 512 threads, 2 gate rows each (tid, tid+512). Per thread 128 u32 of weights:
// 80 in TEN NAMED u32x8 SSA values (fits the PROVEN 128-VGPR grant at 512 thr,
// demand ~110) + 48 via LDS (96KB). h kept quantized int8 (scale 1/64) in LDS.
// Gates: thread j<256 owns (i_j, g_j); j+256 owns (f_j, o_j); sig(f),sig(o)
// exchanged via LDS. Input-side preacts G are exact f32.
__global__ __launch_bounds__(512, 1)
void lstm_rec(const u32* wreg8, const u32* wlds8, const float* rowscale,
              const float* G, const float* h0, const float* c0, float* H) {
    __shared__ u32 Wl[12 * 1024 * 2];      // 96KB, [12][1024][2]
    __shared__ float fo[2][256];           // sig(f), sig(o)
    __shared__ __align__(16) u32 h2q[64];  // 256 int8 of h (byte j = h[j])
    int tid = threadIdx.x;
    int dir = blockIdx.x;
    {   // stage LDS weight slice, vectorized
        const uint4* src = (const uint4*)(wlds8 + (size_t)dir * 12 * 1024 * 2);
        uint4* dst = (uint4*)Wl;
        for (int i = tid; i < 12 * 1024 * 2 / 4; i += 512) dst[i] = src[i];
    }
    const u32x8* p0 = (const u32x8*)(wreg8 + ((size_t)dir * 1024 + tid) * 40);
    const u32x8* p1 = (const u32x8*)(wreg8 + ((size_t)dir * 1024 + tid + 512) * 40);
    u32x8 wq00 = p0[0], wq01 = p0[1], wq02 = p0[2], wq03 = p0[3], wq04 = p0[4];
    u32x8 wq10 = p1[0], wq11 = p1[1], wq12 = p1[2], wq13 = p1[3], wq14 = p1[4];
    float cr0 = rowscale[dir * 1024 + tid];
    float cr1 = rowscale[dir * 1024 + tid + 512];
    float cst = 0.0f;
    if (tid < 256) {
        cst = c0[dir * HD + tid];
        float hv = h0[dir * HD + tid];
        hv = fminf(fmaxf(hv, -1.984375f), 1.984375f);   // h0 ~ N(0,1), clamp to scale range
        ((signed char*)h2q)[tid] = (signed char)(int)rintf(hv * 64.f);
    }
    __syncthreads();
    const float* Gd = G + (size_t)dir * TT * G4;
    float* Hd = H + (size_t)dir * TT * HD;
    for (int t = 0; t < TT; t++) {
        float g0 = Gd[(size_t)t * G4 + tid];          // issued early
        float g1 = Gd[(size_t)t * G4 + tid + 512];
        int acc0 = 0, acc1 = 0;
        DOTQ(wq00, wq10, 0)  DOTQ(wq01, wq11, 8)  DOTQ(wq02, wq12, 16)
        DOTQ(wq03, wq13, 24) DOTQ(wq04, wq14, 32)
#pragma unroll
        for (int q = 0; q < 12; q++) {   // elems 160..255 from LDS (b64 reads)
            uint2 hh = *((const uint2*)&h2q[40 + 2 * q]);
            uint2 pa = *((const uint2*)&Wl[((size_t)q * 1024 + tid) * 2]);
            uint2 pb = *((const uint2*)&Wl[((size_t)q * 1024 + tid + 512) * 2]);
            acc0 = sdot4e(pa.x, hh.x, acc0); acc1 = sdot4e(pb.x, hh.x, acc1);
            acc0 = sdot4e(pa.y, hh.y, acc0); acc1 = sdot4e(pb.y, hh.y, acc1);
        }
        float e0 = (float)acc0 * cr0 + g0;
        float e1 = (float)acc1 * cr1 + g1;
        if (tid >= 256) {                    // e0 = f_j, e1 = o_j  (j = tid-256)
            fo[0][tid - 256] = sigmf_(e0);
            fo[1][tid - 256] = sigmf_(e1);
        }
        __syncthreads();
        if (tid < 256) {                     // e0 = i_j, e1 = g_j  (j = tid)
            float sf = fo[0][tid], so = fo[1][tid];
            cst = sf * cst + sigmf_(e0) * tanhf_(e1);
            float h = so * tanhf_(cst);
            Hd[(size_t)t * HD + tid] = h;
            ((signed char*)h2q)[tid] = (signed char)(int)rintf(h * 64.f);  // |h|<1
        }
        __syncthreads();
    }
}

// K3: feats[t][n] = hf[t]·w_out[n][0:256] + hb_scan[T-1-t]·w_out[n][256:512] + b_out[n]
__global__ __launch_bounds__(256) void feats_kernel(const float* H, const float* w_out,
                                                    const float* b_out, float* feats) {
    int idx = blockIdx.x * blockDim.x + threadIdx.x;
    int t = idx >> 4, n = idx & 15;
    const float* hf = H + (size_t)t * HD;
    const float* hb = H + ((size_t)TT + (TT - 1 - t)) * HD;
    const float* w = w_out + (size_t)n * (2 * HD);
    float a = b_out[n];
    for (int k = 0; k < HD; k += 4) {
        float4 h4 = *((const float4*)&hf[k]);
        float4 w4 = *((const float4*)&w[k]);
        a += h4.x * w4.x + h4.y * w4.y + h4.z * w4.z + h4.w * w4.w;
    }
    for (int k = 0; k < HD; k += 4) {
        float4 h4 = *((const float4*)&hb[k]);
        float4 w4 = *((const float4*)&w[HD + k]);
        a += h4.x * w4.x + h4.y * w4.y + h4.z * w4.z + h4.w * w4.w;
    }
    feats[(size_t)t * NT + n] = a;
}

// K4: Viterbi + backtrack, single wave, shuffle-only recurrence.
// feats staged into LDS in 256-step chunks.
__global__ __launch_bounds__(64) void viterbi_kernel(const float* feats, const float* trans,
                                                     float* out) {
    __shared__ float fl[4096];              // 16KB: 256 steps x 16 tags
    __shared__ float fvs[NT];
    __shared__ unsigned char bps[TT][NT];   // 32KB
    int lane = threadIdx.x;
    int n = lane >> 2, pg = lane & 3;
    float4 tr4 = *((const float4*)&trans[n * NT + pg * 4]);
    float fv = (lane == START_TAG) ? 0.0f : NEGV;
    for (int c = 0; c < TT / 256; c++) {
        float4 st[16];
        const float4* src = (const float4*)(feats + c * 4096);
#pragma unroll
        for (int i = 0; i < 16; i++) st[i] = src[i * 64 + lane];
#pragma unroll
        for (int i = 0; i < 16; i++) *((float4*)&fl[(i * 64 + lane) * 4]) = st[i];
        __syncthreads();
        for (int tt = 0; tt < 256; tt++) {
            int t = c * 256 + tt;
            float f0 = __shfl(fv, pg * 4 + 0, 64);
            float f1 = __shfl(fv, pg * 4 + 1, 64);
            float f2 = __shfl(fv, pg * 4 + 2, 64);
            float f3 = __shfl(fv, pg * 4 + 3, 64);
            float ft = fl[tt * 16 + n];
            float v = f0 + tr4.x; int bi = pg * 4 + 0;
            float v1 = f1 + tr4.y; if (v1 > v) { v = v1; bi = pg * 4 + 1; }
            float v2 = f2 + tr4.z; if (v2 > v) { v = v2; bi = pg * 4 + 2; }
            float v3 = f3 + tr4.w; if (v3 > v) { v = v3; bi = pg * 4 + 3; }
#pragma unroll
            for (int m = 1; m <= 2; m <<= 1) {   // first-index tie-break
                float ov = __shfl_xor(v, m, 64);
                int ob = __shfl_xor(bi, m, 64);
                if (ov > v || (ov == v && ob < bi)) { v = ov; bi = ob; }
            }
            if (pg == 0) bps[t][n] = (unsigned char)bi;
            fv = __shfl(v + ft, (lane & 15) * 4, 64);
        }
        __syncthreads();
    }
    if (lane < NT) fvs[lane] = fv;
    __syncthreads();
    if (lane == 0) {
        float best = -3.0e38f; int bt = 0;
        for (int p = 0; p < NT; p++) {
            float tv = fvs[p] + trans[STOP_TAG * NT + p];
            if (tv > best) { best = tv; bt = p; }
        }
        out[0] = best;
        int tag = bt;
        out[TT] = (float)tag;                  // path[T-1]
        for (int t = TT - 2; t >= 0; t--) {
            tag = bps[t + 1][tag];
            out[1 + t] = (float)tag;
        }
    }
}

extern "C" void kernel_launch(void* const* d_in, const int* in_sizes, int n_in,
                              void* d_out, int out_size, void* d_ws, size_t ws_size,
                              hipStream_t stream) {
    const int* sent = (const int*)d_in[0];
    const float* embed = (const float*)d_in[1];
    const float* wih_f = (const float*)d_in[2];
    const float* whh_f = (const float*)d_in[3];
    const float* b_f = (const float*)d_in[4];
    const float* wih_b = (const float*)d_in[5];
    const float* whh_b = (const float*)d_in[6];
    const float* b_b = (const float*)d_in[7];
    const float* w_out = (const float*)d_in[8];
    const float* b_out = (const float*)d_in[9];
    const float* trans = (const float*)d_in[10];
    const float* h0 = (const float*)d_in[11];
    const float* c0 = (const float*)d_in[12];
    float* out = (float*)d_out;
    char* ws = (char*)d_ws;

    float* G = (float*)(ws);                                    // 16MB
    float* H = (float*)(ws + (size_t)16 * 1024 * 1024);         // 4MB
    float* feats = (float*)(ws + (size_t)20 * 1024 * 1024);     // 128KB
    u32* wreg8 = (u32*)(ws + (size_t)21 * 1024 * 1024);         // 320KB
    u32* wlds8 = (u32*)(ws + (size_t)21 * 1024 * 1024 + 512 * 1024);  // 192KB
    float* rowscale = (float*)(ws + (size_t)22 * 1024 * 1024);  // 8KB

    pack_q8<<<dim3(512), 256, 0, stream>>>(whh_f, whh_b, wreg8, wlds8, rowscale);
    input_gemm<<<dim3(TT / 32, G4 / 256, 2), 256, 0, stream>>>(sent, embed, wih_f, b_f,
                                                               wih_b, b_b, G);
    lstm_rec<<<dim3(2), 512, 0, stream>>>(wreg8, wlds8, rowscale, G, h0, c0, H);
    feats_kernel<<<dim3(TT * NT / 256), 256, 0, stream>>>(H, w_out, b_out, feats);
    viterbi_kernel<<<dim3(1), 64, 0, stream>>>(feats, trans, out);
}

// Round 8
// 2732.490 us; speedup vs baseline: 2.1582x; 1.0553x over previous
//
#include <hip/hip_runtime.h>

typedef unsigned int u32;
typedef u32 u32x8 __attribute__((ext_vector_type(8)));

#define TT 2048
#define HD 256
#define G4 1024
#define NT 16
#define START_TAG 14
#define STOP_TAG 15
#define NEGV (-10000.0f)

__device__ __forceinline__ int sdot4e(u32 a, u32 b, int c) {
#if __has_builtin(__builtin_amdgcn_sdot4)
    return __builtin_amdgcn_sdot4((int)a, (int)b, c, false);
#else
    c += (int)(signed char)(a & 255) * (int)(signed char)(b & 255);
    c += (int)(signed char)((a >> 8) & 255) * (int)(signed char)((b >> 8) & 255);
    c += (int)(signed char)((a >> 16) & 255) * (int)(signed char)((b >> 16) & 255);
    c += (int)(signed char)(a >> 24) * (int)(signed char)(b >> 24);
    return c;
#endif
}
__device__ __forceinline__ float sigmf_(float x) { return 1.0f / (1.0f + __expf(-x)); }
__device__ __forceinline__ float tanhf_(float x) {
    float e = __expf(-2.0f * fabsf(x));
    return copysignf((1.0f - e) / (1.0f + e), x);
}

// K0: quantize w_hh to int8, per-row scale. One wave per row; lane packs u32 of
// elems 4*lane..4*lane+3. lane<48 -> register file [dir][1024][48];
// lane>=48 -> LDS file [dir][4][1024][4] (b128-chunked: q4 = (lane-48)>>2, rr = (lane-48)&3).
__global__ __launch_bounds__(256) void pack_q8(const float* whh_f, const float* whh_b,
                                               u32* wreg8, u32* wlds8, float* rowscale) {
    int lane = threadIdx.x & 63;
    int row = blockIdx.x * 4 + (threadIdx.x >> 6);   // 0..2047
    int dir = row >> 10, r = row & 1023;
    const float* w = (dir ? whh_b : whh_f) + (size_t)r * HD + lane * 4;
    float4 v = *((const float4*)w);
    float m = fmaxf(fmaxf(fabsf(v.x), fabsf(v.y)), fmaxf(fabsf(v.z), fabsf(v.w)));
    for (int off = 1; off < 64; off <<= 1) m = fmaxf(m, __shfl_xor(m, off, 64));
    float invs = m > 0.f ? 127.f / m : 0.f;
    int q0 = (int)rintf(v.x * invs), q1 = (int)rintf(v.y * invs);
    int q2 = (int)rintf(v.z * invs), q3 = (int)rintf(v.w * invs);
    u32 pk = (u32)(q0 & 255) | ((u32)(q1 & 255) << 8) |
             ((u32)(q2 & 255) << 16) | ((u32)(q3 & 255) << 24);
    if (lane < 48) {
        wreg8[((size_t)(dir * 1024 + r)) * 48 + lane] = pk;
    } else {
        int q = lane - 48, q4 = q >> 2, rr = q & 3;
        wlds8[(((size_t)(dir * 4 + q4)) * 1024 + r) * 4 + rr] = pk;
    }
    if (lane == 0) rowscale[dir * 1024 + r] = m * (1.0f / (127.f * 64.f));
}

// K1: G[dir][t][r] = dot(embed[sent[t or T-1-t]], w_ih[r]) + b[r]   (f32 exact)
__global__ __launch_bounds__(256) void input_gemm(const int* sent, const float* embed,
                                                  const float* wih_f, const float* b_f,
                                                  const float* wih_b, const float* b_b,
                                                  float* G) {
    __shared__ float X[32][HD];   // 32KB
    __shared__ int rows[32];
    int tid = threadIdx.x;
    int dir = blockIdx.z;
    int t0 = blockIdx.x * 32;
    if (tid < 32) {
        int tg = t0 + tid;
        rows[tid] = sent[dir ? (TT - 1 - tg) : tg];
    }
    __syncthreads();
    for (int i = 0; i < 32; i++) X[i][tid] = embed[(size_t)rows[i] * HD + tid];
    __syncthreads();
    int r = blockIdx.y * 256 + tid;
    const float* wrow = (dir ? wih_b : wih_f) + (size_t)r * HD;
    float acc[32];
#pragma unroll
    for (int i = 0; i < 32; i++) acc[i] = 0.0f;
    for (int kc = 0; kc < HD / 4; kc++) {
        float4 w4 = ((const float4*)wrow)[kc];
#pragma unroll
        for (int i = 0; i < 32; i++) {
            float4 x4 = *((const float4*)&X[i][kc * 4]);
            acc[i] += w4.x * x4.x + w4.y * x4.y + w4.z * x4.z + w4.w * x4.w;
        }
    }
    float bias = (dir ? b_b : b_f)[r];
    for (int i = 0; i < 32; i++)
        G[((size_t)dir * TT + t0 + i) * G4 + r] = acc[i] + bias;
}

// int8 dot block: W0/W1 = 8 u32 (32 int8) of rows tid / tid+512; h2q[HB..HB+7].
#define DOTQ(W0, W1, HB)                                                      \
    {                                                                         \
        uint4 pa = *((const uint4*)&h2q[(HB)]);                               \
        acc0 = sdot4e(W0[0], pa.x, acc0); acc1 = sdot4e(W1[0], pa.x, acc1);   \
        acc0 = sdot4e(W0[1], pa.y, acc0); acc1 = sdot4e(W1[1], pa.y, acc1);   \
        acc0 = sdot4e(W0[2], pa.z, acc0); acc1 = sdot4e(W1[2], pa.z, acc1);   \
        acc0 = sdot4e(W0[3], pa.w, acc0); acc1 = sdot4e(W1[3], pa.w, acc1);   \
        uint4 pb = *((const uint4*)&h2q[(HB) + 4]);                           \
        acc0 = sdot4e(W0[4], pb.x, acc0); acc1 = sdot4e(W1[4], pb.x, acc1);   \
        acc0 = sdot4e(W0[5], pb.y, acc0); acc1 = sdot4e(W1[5], pb.y, acc1);   \
        acc0 = sdot4e(W0[6], pb.z, acc0); acc1 = sdot4e(W1[6], pb.z, acc1);   \
        acc0 = sdot4e(W0[7], pb.w, acc0); acc1 = sdot4e(W1[7], pb.w, acc1);   \
    }

// K2: persistent per-direction LSTM recurrence, int8 weights (v_dot4).
// 512 threads, 2 gate rows each (tid, tid+512). Per thread 128 u32 of weights:
// 96 in TWELVE NAMED u32x8 SSA values (R7 measured misc ~8 regs -> demand ~104
// fits the 128 grant) + 32 via LDS [4][1024][4] (64KB, ds_read_b128, ALL
// offsets immediate: q4*16384+8192 <= 57344 < 64K). h int8 (scale 1/64) in LDS.
// Activation balanced: pre-barrier each half does its own transcendentals.
__global__ __launch_bounds__(512, 1)
void lstm_rec(const u32* wreg8, const u32* wlds8, const float* rowscale,
              const float* G, const float* h0, const float* c0, float* H) {
    __shared__ u32 Wl[4 * 1024 * 4];       // 64KB, [4][1024][4]
    __shared__ float fo[2][256];           // sig(f), sig(o)
    __shared__ __align__(16) u32 h2q[64];  // 256 int8 of h (byte j = h[j])
    int tid = threadIdx.x;
    int dir = blockIdx.x;
    {   // stage LDS weight slice, vectorized (linear copy preserves layout)
        const uint4* src = (const uint4*)(wlds8 + (size_t)dir * 4 * 1024 * 4);
        uint4* dst = (uint4*)Wl;
        for (int i = tid; i < 4 * 1024; i += 512) dst[i] = src[i];
    }
    const u32x8* p0 = (const u32x8*)(wreg8 + ((size_t)dir * 1024 + tid) * 48);
    const u32x8* p1 = (const u32x8*)(wreg8 + ((size_t)dir * 1024 + tid + 512) * 48);
    u32x8 wq00 = p0[0], wq01 = p0[1], wq02 = p0[2],
          wq03 = p0[3], wq04 = p0[4], wq05 = p0[5];
    u32x8 wq10 = p1[0], wq11 = p1[1], wq12 = p1[2],
          wq13 = p1[3], wq14 = p1[4], wq15 = p1[5];
    float cr0 = rowscale[dir * 1024 + tid];
    float cr1 = rowscale[dir * 1024 + tid + 512];
    float cst = 0.0f;
    if (tid < 256) {
        cst = c0[dir * HD + tid];
        float hv = h0[dir * HD + tid];
        hv = fminf(fmaxf(hv, -1.984375f), 1.984375f);
        ((signed char*)h2q)[tid] = (signed char)(int)rintf(hv * 64.f);
    }
    __syncthreads();
    const float* Gd = G + (size_t)dir * TT * G4;
    float* Hd = H + (size_t)dir * TT * HD;
    for (int t = 0; t < TT; t++) {
        float g0 = Gd[(size_t)t * G4 + tid];          // issued early
        float g1 = Gd[(size_t)t * G4 + tid + 512];
        int acc0 = 0, acc1 = 0;
        DOTQ(wq00, wq10, 0)  DOTQ(wq01, wq11, 8)  DOTQ(wq02, wq12, 16)
        DOTQ(wq03, wq13, 24) DOTQ(wq04, wq14, 32) DOTQ(wq05, wq15, 40)
#pragma unroll
        for (int q4 = 0; q4 < 4; q4++) {   // elems 192..255: b128 reads, imm offsets
            uint4 hh = *((const uint4*)&h2q[48 + q4 * 4]);
            uint4 wa = *((const uint4*)&Wl[((size_t)q4 * 1024 + tid) * 4]);
            uint4 wb = *((const uint4*)&Wl[((size_t)q4 * 1024 + tid + 512) * 4]);
            acc0 = sdot4e(wa.x, hh.x, acc0); acc1 = sdot4e(wb.x, hh.x, acc1);
            acc0 = sdot4e(wa.y, hh.y, acc0); acc1 = sdot4e(wb.y, hh.y, acc1);
            acc0 = sdot4e(wa.z, hh.z, acc0); acc1 = sdot4e(wb.z, hh.z, acc1);
            acc0 = sdot4e(wa.w, hh.w, acc0); acc1 = sdot4e(wb.w, hh.w, acc1);
        }
        float e0 = (float)acc0 * cr0 + g0;
        float e1 = (float)acc1 * cr1 + g1;
        float x0, x1;
        if (tid >= 256) {                    // e0 = f_j, e1 = o_j  (j = tid-256)
            fo[0][tid - 256] = sigmf_(e0);
            fo[1][tid - 256] = sigmf_(e1);
        } else {                             // e0 = i_j, e1 = g_j: own transcendentals
            x0 = sigmf_(e0);                 // sig(i)
            x1 = tanhf_(e1);                 // tanh(g)
        }
        __syncthreads();
        if (tid < 256) {
            float sf = fo[0][tid], so = fo[1][tid];
            cst = sf * cst + x0 * x1;
            float h = so * tanhf_(cst);
            Hd[(size_t)t * HD + tid] = h;
            ((signed char*)h2q)[tid] = (signed char)(int)rintf(h * 64.f);  // |h|<1
        }
        __syncthreads();
    }
}

// K3: feats[t][n] = hf[t]·w_out[n][0:256] + hb_scan[T-1-t]·w_out[n][256:512] + b_out[n]
__global__ __launch_bounds__(256) void feats_kernel(const float* H, const float* w_out,
                                                    const float* b_out, float* feats) {
    int idx = blockIdx.x * blockDim.x + threadIdx.x;
    int t = idx >> 4, n = idx & 15;
    const float* hf = H + (size_t)t * HD;
    const float* hb = H + ((size_t)TT + (TT - 1 - t)) * HD;
    const float* w = w_out + (size_t)n * (2 * HD);
    float a = b_out[n];
    for (int k = 0; k < HD; k += 4) {
        float4 h4 = *((const float4*)&hf[k]);
        float4 w4 = *((const float4*)&w[k]);
        a += h4.x * w4.x + h4.y * w4.y + h4.z * w4.z + h4.w * w4.w;
    }
    for (int k = 0; k < HD; k += 4) {
        float4 h4 = *((const float4*)&hb[k]);
        float4 w4 = *((const float4*)&w[HD + k]);
        a += h4.x * w4.x + h4.y * w4.y + h4.z * w4.z + h4.w * w4.w;
    }
    feats[(size_t)t * NT + n] = a;
}

// K4: Viterbi + backtrack, single wave, shuffle-only recurrence.
// feats staged into LDS in 256-step chunks.
__global__ __launch_bounds__(64) void viterbi_kernel(const float* feats, const float* trans,
                                                     float* out) {
    __shared__ float fl[4096];              // 16KB: 256 steps x 16 tags
    __shared__ float fvs[NT];
    __shared__ unsigned char bps[TT][NT];   // 32KB
    int lane = threadIdx.x;
    int n = lane >> 2, pg = lane & 3;
    float4 tr4 = *((const float4*)&trans[n * NT + pg * 4]);
    float fv = (lane == START_TAG) ? 0.0f : NEGV;
    for (int c = 0; c < TT / 256; c++) {
        float4 st[16];
        const float4* src = (const float4*)(feats + c * 4096);
#pragma unroll
        for (int i = 0; i < 16; i++) st[i] = src[i * 64 + lane];
#pragma unroll
        for (int i = 0; i < 16; i++) *((float4*)&fl[(i * 64 + lane) * 4]) = st[i];
        __syncthreads();
        for (int tt = 0; tt < 256; tt++) {
            int t = c * 256 + tt;
            float f0 = __shfl(fv, pg * 4 + 0, 64);
            float f1 = __shfl(fv, pg * 4 + 1, 64);
            float f2 = __shfl(fv, pg * 4 + 2, 64);
            float f3 = __shfl(fv, pg * 4 + 3, 64);
            float ft = fl[tt * 16 + n];
            float v = f0 + tr4.x; int bi = pg * 4 + 0;
            float v1 = f1 + tr4.y; if (v1 > v) { v = v1; bi = pg * 4 + 1; }
            float v2 = f2 + tr4.z; if (v2 > v) { v = v2; bi = pg * 4 + 2; }
            float v3 = f3 + tr4.w; if (v3 > v) { v = v3; bi = pg * 4 + 3; }
#pragma unroll
            for (int m = 1; m <= 2; m <<= 1) {   // first-index tie-break
                float ov = __shfl_xor(v, m, 64);
                int ob = __shfl_xor(bi, m, 64);
                if (ov > v || (ov == v && ob < bi)) { v = ov; bi = ob; }
            }
            if (pg == 0) bps[t][n] = (unsigned char)bi;
            fv = __shfl(v + ft, (lane & 15) * 4, 64);
        }
        __syncthreads();
    }
    if (lane < NT) fvs[lane] = fv;
    __syncthreads();
    if (lane == 0) {
        float best = -3.0e38f; int bt = 0;
        for (int p = 0; p < NT; p++) {
            float tv = fvs[p] + trans[STOP_TAG * NT + p];
            if (tv > best) { best = tv; bt = p; }
        }
        out[0] = best;
        int tag = bt;
        out[TT] = (float)tag;                  // path[T-1]
        for (int t = TT - 2; t >= 0; t--) {
            tag = bps[t + 1][tag];
            out[1 + t] = (float)tag;
        }
    }
}

extern "C" void kernel_launch(void* const* d_in, const int* in_sizes, int n_in,
                              void* d_out, int out_size, void* d_ws, size_t ws_size,
                              hipStream_t stream) {
    const int* sent = (const int*)d_in[0];
    const float* embed = (const float*)d_in[1];
    const float* wih_f = (const float*)d_in[2];
    const float* whh_f = (const float*)d_in[3];
    const float* b_f = (const float*)d_in[4];
    const float* wih_b = (const float*)d_in[5];
    const float* whh_b = (const float*)d_in[6];
    const float* b_b = (const float*)d_in[7];
    const float* w_out = (const float*)d_in[8];
    const float* b_out = (const float*)d_in[9];
    const float* trans = (const float*)d_in[10];
    const float* h0 = (const float*)d_in[11];
    const float* c0 = (const float*)d_in[12];
    float* out = (float*)d_out;
    char* ws = (char*)d_ws;

    float* G = (float*)(ws);                                    // 16MB
    float* H = (float*)(ws + (size_t)16 * 1024 * 1024);         // 4MB
    float* feats = (float*)(ws + (size_t)20 * 1024 * 1024);     // 128KB
    u32* wreg8 = (u32*)(ws + (size_t)21 * 1024 * 1024);         // 384KB
    u32* wlds8 = (u32*)(ws + (size_t)21 * 1024 * 1024 + 512 * 1024);  // 128KB
    float* rowscale = (float*)(ws + (size_t)22 * 1024 * 1024);  // 8KB

    pack_q8<<<dim3(512), 256, 0, stream>>>(whh_f, whh_b, wreg8, wlds8, rowscale);
    input_gemm<<<dim3(TT / 32, G4 / 256, 2), 256, 0, stream>>>(sent, embed, wih_f, b_f,
                                                               wih_b, b_b, G);
    lstm_rec<<<dim3(2), 512, 0, stream>>>(wreg8, wlds8, rowscale, G, h0, c0, H);
    feats_kernel<<<dim3(TT * NT / 256), 256, 0, stream>>>(H, w_out, b_out, feats);
    viterbi_kernel<<<dim3(1), 64, 0, stream>>>(feats, trans, out);
}